// Round 1
// baseline (47.390 us; speedup 1.0000x reference)
//
#include <hip/hip_runtime.h>

// DilateAttention: q,k,v [B=16, d=32, H=128, W=128] fp32, kernel=3, dilation=2, pad=2.
// Per-pixel 1x9 attention over dilated window; OOB taps are zero-padded (score 0,
// value 0) and DO participate in the softmax denominator.

#define BB 16
#define HD 32
#define HH 128
#define WW 128

__global__ __launch_bounds__(128) void dilate_attn_kernel(
    const float* __restrict__ q,
    const float* __restrict__ k,
    const float* __restrict__ v,
    float* __restrict__ out)
{
    const int w = threadIdx.x;               // 0..127
    const int h = blockIdx.x & (HH - 1);     // 0..127
    const int b = blockIdx.x >> 7;           // 0..15

    const int plane = HH * WW;               // 16384
    const int base = (b * HD) * plane + h * WW + w;

    // 9 dilated taps: (h-2+2i, w-2+2j), row-major (i outer, j inner) to match
    // torch nn.Unfold ordering used by the reference.
    bool valid[9];
    int off[9];
    #pragma unroll
    for (int i = 0; i < 3; ++i) {
        #pragma unroll
        for (int j = 0; j < 3; ++j) {
            const int n = i * 3 + j;
            const int hh = h + i * 2 - 2;
            const int wc = w + j * 2 - 2;
            valid[n] = (hh >= 0) && (hh < HH) && (wc >= 0) && (wc < WW);
            off[n] = (i * 2 - 2) * WW + (j * 2 - 2);
        }
    }

    // ---- Pass 1: scores[n] = sum_d q[d] * k_tap[n][d] ----
    float s[9];
    #pragma unroll
    for (int n = 0; n < 9; ++n) s[n] = 0.f;

    const float* qp = q + base;
    const float* kp = k + base;
    #pragma unroll 4
    for (int d = 0; d < HD; ++d) {
        const float qd = qp[d * plane];
        #pragma unroll
        for (int n = 0; n < 9; ++n) {
            const float kt = valid[n] ? kp[d * plane + off[n]] : 0.f;
            s[n] = fmaf(qd, kt, s[n]);
        }
    }

    // ---- Softmax over the 9 taps (scaled) ----
    const float scale = 0.17677669529663687f;  // 32^-0.5
    float m = -3.4e38f;
    #pragma unroll
    for (int n = 0; n < 9; ++n) { s[n] *= scale; m = fmaxf(m, s[n]); }
    float sum = 0.f;
    #pragma unroll
    for (int n = 0; n < 9; ++n) { s[n] = __expf(s[n] - m); sum += s[n]; }
    const float inv = 1.f / sum;
    #pragma unroll
    for (int n = 0; n < 9; ++n) s[n] *= inv;

    // ---- Pass 2: out[d] = sum_n attn[n] * v_tap[n][d] ----
    const float* vp = v + base;
    float* op = out + base;
    #pragma unroll 4
    for (int d = 0; d < HD; ++d) {
        float acc = 0.f;
        #pragma unroll
        for (int n = 0; n < 9; ++n) {
            const float vt = valid[n] ? vp[d * plane + off[n]] : 0.f;
            acc = fmaf(s[n], vt, acc);
        }
        op[d * plane] = acc;
    }
}

extern "C" void kernel_launch(void* const* d_in, const int* in_sizes, int n_in,
                              void* d_out, int out_size, void* d_ws, size_t ws_size,
                              hipStream_t stream) {
    const float* q = (const float*)d_in[0];
    const float* k = (const float*)d_in[1];
    const float* v = (const float*)d_in[2];
    float* out = (float*)d_out;

    // One block per (b, h) row; one thread per w.
    dim3 grid(BB * HH);
    dim3 block(WW);
    dilate_attn_kernel<<<grid, block, 0, stream>>>(q, k, v, out);
}